// Round 5
// baseline (1249.378 us; speedup 1.0000x reference)
//
#include <hip/hip_runtime.h>

// NNMF fused: B=8192, NIN=3072, NOUT=512, 5 iterations.
// R5: BT=64 (128 blocks) to halve L2 W-traffic per unit work. Wave-specialized:
// waves 0-3 (A) produce r (quarter-k split each, h bf16 operands from LDS);
// waves 4-7 (B) consume r -> tacc (128 acc regs). fp32 h persists in d_out
// across iterations (read@boundary, write@boundary). W rolling register
// prefetch, 32 MFMAs cover per 8-frag batch (2x R4's ratio).

#define NIN 3072
#define NOUT 512

using bf16x8 = __attribute__((ext_vector_type(8))) short;
using f32x4  = __attribute__((ext_vector_type(4))) float;

__device__ __forceinline__ unsigned short f2bf(float f) {
    unsigned int u = __builtin_bit_cast(unsigned int, f);
    return (unsigned short)((u + 0x7fffu + ((u >> 16) & 1u)) >> 16);  // RNE
}
__device__ __forceinline__ float bf2f(unsigned short s) {
    unsigned int u = ((unsigned int)s) << 16;
    return __builtin_bit_cast(float, u);
}

// ---------------------------------------------------------------------------
// prep_w: shuffle W (fp32 [512][3072]) into MFMA-frag-native bf16 buffers.
// (verified R2-R4 — unchanged)
// ---------------------------------------------------------------------------
__global__ void prep_w(const float* __restrict__ W,
                       unsigned short* __restrict__ W1,
                       unsigned short* __restrict__ W2) {
    int t = blockIdx.x * 256 + threadIdx.x;   // 0 .. 393215
    const int half = 196608;
    if (t < half) {
        int f = t >> 6, l = t & 63;
        int kcg = f >> 5, nt = f & 31;
        int n = nt * 16 + (l & 15);
        int k = kcg * 32 + ((l >> 4) << 3);
        unsigned short* dst = W2 + (size_t)t * 8;
        const float* src = W + (size_t)n * NIN + k;
        #pragma unroll
        for (int j = 0; j < 8; ++j) dst[j] = f2bf(src[j]);
    } else {
        int u = t - half;
        int f = u >> 6, l = u & 63;
        int ktg = f >> 4, nc = f & 15;
        int k = ktg * 16 + (l & 15);
        int nb = nc * 32 + ((l >> 4) << 3);
        unsigned short* dst = W1 + (size_t)u * 8;
        #pragma unroll
        for (int j = 0; j < 8; ++j) dst[j] = f2bf(W[(size_t)(nb + j) * NIN + k]);
    }
}

// ---------------------------------------------------------------------------
// prep_sum: invsum[b] = 1/(sum_k x[b][k] + eps). One wave per row.
// ---------------------------------------------------------------------------
__global__ void prep_sum(const float* __restrict__ x, float* __restrict__ invsum) {
    int row = blockIdx.x;
    int lane = threadIdx.x;  // 64
    const float4* r4 = reinterpret_cast<const float4*>(x + (size_t)row * NIN);
    float s = 0.f;
    #pragma unroll
    for (int c = 0; c < 12; ++c) {
        float4 v = r4[c * 64 + lane];
        s += v.x + v.y + v.z + v.w;
    }
    #pragma unroll
    for (int off = 32; off > 0; off >>= 1) s += __shfl_down(s, off, 64);
    if (lane == 0) invsum[row] = 1.0f / (s + 1e-20f);
}

// ---------------------------------------------------------------------------
// prep_xt: x pre-normalized bf16, ordered so each main A-thread reads its 32
// r-phase x values as one contiguous 64B chunk per slot.
//   X2T[((blk*24+s)*256 + t)*32 + j],  t = aw*64 + l,  j = m*8 + kt*4 + i
//   row = blk*64 + m*16 + (l>>4)*4 + i;  col = s*128 + aw*32 + kt*16 + (l&15)
// ---------------------------------------------------------------------------
__global__ void prep_xt(const float* __restrict__ x, const float* __restrict__ invsum,
                        unsigned short* __restrict__ X2T) {
    int bb = blockIdx.x;            // 0..3071
    int blk = bb / 24, s = bb % 24;
    int t = threadIdx.x;            // 256
    int aw = t >> 6, l = t & 63, lo = l & 15, hi = l >> 4;
    unsigned short o[32];
    #pragma unroll
    for (int j = 0; j < 32; ++j) {
        int m = j >> 3, kt = (j >> 2) & 1, i = j & 3;
        int row = blk * 64 + m * 16 + hi * 4 + i;
        int col = s * 128 + aw * 32 + kt * 16 + lo;
        o[j] = f2bf(x[(size_t)row * NIN + col] * invsum[row]);
    }
    unsigned short* dst = X2T + (((size_t)blk * 24 + s) * 256 + t) * 32;
    #pragma unroll
    for (int c = 0; c < 4; ++c)
        *reinterpret_cast<uint4*>(dst + c * 8) = *reinterpret_cast<uint4*>(o + c * 8);
}

// ---------------------------------------------------------------------------
// Main kernel. 128 blocks x 512 threads, 64 rows/block.
// A waves (0-3): wave aw covers k-cols [aw*32, aw*32+32) of each 128-slice,
//   all 64 rows (4 m-tiles), h operands from h_lds, W1 rolling regs.
// B waves (4-7): wave bw covers n-cols [bw*128, ...+128), all 64 rows,
//   r from r_lds (1 slot behind), W2 rolling regs, tacc[4][8] f32x4.
// fp32 h lives in `out` between iterations.
// ---------------------------------------------------------------------------
__global__ __launch_bounds__(512, 2) void nnmf_main(
    const unsigned short* __restrict__ X2T,
    const unsigned short* __restrict__ W1,
    const unsigned short* __restrict__ W2,
    const float* __restrict__ h_init,
    float* __restrict__ out)
{
    __shared__ unsigned short h_lds[64 * 520];     // 66.6 KB bf16 h operand cache
    __shared__ unsigned short r_lds[2][64 * 136];  // 34.8 KB double-buffered r
    __shared__ float red[4][64];

    const int tid = threadIdx.x;
    const int wv = tid >> 6, l = tid & 63, lo = l & 15, hi = l >> 4;
    const int b0 = blockIdx.x * 64;

    // init h_lds from h_initial (same value for every row)
    for (int idx = tid; idx < 64 * 512; idx += 512) {
        int r = idx >> 9, c = idx & 511;
        h_lds[r * 520 + c] = f2bf(h_init[c]);
    }

    if (wv < 4) {
        // ================= A path (producer) =================
        const int aw = wv;
        const unsigned short* w1b = W1 + (size_t)aw * 16384 + (size_t)l * 8; // +s*65536 +kt*8192 +nc*512
        const unsigned short* xb  = X2T + (((size_t)blockIdx.x * 24) * 256 + (size_t)tid) * 32;

        bf16x8 w1p[8], w1q[8];
        // prime: w1p <- (s=0, nc 0..3)
        #pragma unroll
        for (int kt = 0; kt < 2; ++kt)
            #pragma unroll
            for (int n4 = 0; n4 < 4; ++n4)
                w1p[kt * 4 + n4] = *reinterpret_cast<const bf16x8*>(w1b + kt * 8192 + n4 * 512);

        for (int it = 0; it < 5; ++it) {
            __syncthreads();   // h_lds ready
            for (int s = 0; s < 25; ++s) {
                __syncthreads();
                if (s >= 24) continue;
                const int sn = (s + 1 == 24) ? 0 : s + 1;
                const unsigned short* w1s = w1b + (size_t)s * 65536;
                const unsigned short* w1n = w1b + (size_t)sn * 65536;

                // x for this slot (64B, consumed after the MFMAs)
                union { uint4 v[4]; unsigned short u[32]; } xu;
                const unsigned short* xp = xb + (size_t)s * 8192;
                #pragma unroll
                for (int c = 0; c < 4; ++c)
                    xu.v[c] = *reinterpret_cast<const uint4*>(xp + c * 8);

                f32x4 d[4][2];
                #pragma unroll
                for (int m = 0; m < 4; ++m) { d[m][0] = (f32x4){0,0,0,0}; d[m][1] = (f32x4){0,0,0,0}; }

                // 4 batches of 4 nc; rolling: load batch b+1 while MFMAing batch b
                #pragma unroll
                for (int b = 0; b < 4; ++b) {
                    bf16x8* cur = (b & 1) ? w1q : w1p;
                    bf16x8* nxt = (b & 1) ? w1p : w1q;
                    const unsigned short* src = (b < 3) ? (w1s + (size_t)(b + 1) * 4 * 512)
                                                        : w1n;
                    #pragma unroll
                    for (int kt = 0; kt < 2; ++kt)
                        #pragma unroll
                        for (int n4 = 0; n4 < 4; ++n4)
                            nxt[kt * 4 + n4] = *reinterpret_cast<const bf16x8*>(src + kt * 8192 + n4 * 512);
                    #pragma unroll
                    for (int n4 = 0; n4 < 4; ++n4) {
                        int nc = b * 4 + n4;
                        #pragma unroll
                        for (int m = 0; m < 4; ++m) {
                            bf16x8 ha = *reinterpret_cast<const bf16x8*>(
                                &h_lds[(m * 16 + lo) * 520 + nc * 32 + hi * 8]);
                            d[m][0] = __builtin_amdgcn_mfma_f32_16x16x32_bf16(ha, cur[n4],     d[m][0], 0,0,0);
                            d[m][1] = __builtin_amdgcn_mfma_f32_16x16x32_bf16(ha, cur[4 + n4], d[m][1], 0,0,0);
                        }
                    }
                }

                // r = x * rcp(denom + eps); write r_lds[s&1]
                unsigned short* rb = r_lds[s & 1];
                #pragma unroll
                for (int m = 0; m < 4; ++m)
                    #pragma unroll
                    for (int kt = 0; kt < 2; ++kt)
                        #pragma unroll
                        for (int i = 0; i < 4; ++i) {
                            float xv = bf2f(xu.u[m * 8 + kt * 4 + i]);
                            float rv = xv * __builtin_amdgcn_rcpf(d[m][kt][i] + 1e-20f);
                            rb[(m * 16 + hi * 4 + i) * 136 + aw * 32 + kt * 16 + lo] = f2bf(rv);
                        }
            }
            __syncthreads();   // matches B's red barrier
        }
    } else {
        // ================= B path (consumer) =================
        const int bw = wv - 4;
        const unsigned short* w2b = W2 + (size_t)bw * 4096 + (size_t)l * 8; // +s*65536 +kc*16384 +nt*512

        float h0v[8];
        #pragma unroll
        for (int nt = 0; nt < 8; ++nt) h0v[nt] = h_init[bw * 128 + nt * 16 + lo];

        f32x4 tacc[4][8];
        bf16x8 w2p[8], w2q[8];
        // prime: w2p <- (u=0, kc=0)
        #pragma unroll
        for (int nt = 0; nt < 8; ++nt)
            w2p[nt] = *reinterpret_cast<const bf16x8*>(w2b + nt * 512);

        for (int it = 0; it < 5; ++it) {
            __syncthreads();   // h_lds ready
            #pragma unroll
            for (int m = 0; m < 4; ++m)
                #pragma unroll
                for (int nt = 0; nt < 8; ++nt)
                    tacc[m][nt] = (f32x4){0.f, 0.f, 0.f, 0.f};

            for (int s = 0; s < 25; ++s) {
                __syncthreads();
                if (s < 1) continue;
                const int u = s - 1;
                const int un = (u + 1 == 24) ? 0 : u + 1;
                const unsigned short* w2s = w2b + (size_t)u * 65536;
                const unsigned short* w2n = w2b + (size_t)un * 65536;
                const unsigned short* rb = r_lds[u & 1];

                #pragma unroll
                for (int kc = 0; kc < 4; ++kc) {
                    bf16x8* cur = (kc & 1) ? w2q : w2p;
                    bf16x8* nxt = (kc & 1) ? w2p : w2q;
                    const unsigned short* src = (kc < 3) ? (w2s + (size_t)(kc + 1) * 16384)
                                                         : w2n;
                    #pragma unroll
                    for (int nt = 0; nt < 8; ++nt)
                        nxt[nt] = *reinterpret_cast<const bf16x8*>(src + nt * 512);
                    bf16x8 ra[4];
                    #pragma unroll
                    for (int m = 0; m < 4; ++m)
                        ra[m] = *reinterpret_cast<const bf16x8*>(
                            &rb[(m * 16 + lo) * 136 + kc * 32 + hi * 8]);
                    #pragma unroll
                    for (int nt = 0; nt < 8; ++nt)
                        #pragma unroll
                        for (int m = 0; m < 4; ++m)
                            tacc[m][nt] = __builtin_amdgcn_mfma_f32_16x16x32_bf16(ra[m], cur[nt], tacc[m][nt], 0,0,0);
                }
            }

            // ---- boundary: h_new = normalize(h_old * (1 + t)); h_old fp32 from `out`
            float p[4][4];
            #pragma unroll
            for (int m = 0; m < 4; ++m)
                #pragma unroll
                for (int i = 0; i < 4; ++i) p[m][i] = 0.f;

            #pragma unroll
            for (int m = 0; m < 4; ++m)
                #pragma unroll
                for (int nt = 0; nt < 8; ++nt)
                    #pragma unroll
                    for (int i = 0; i < 4; ++i) {
                        int row = m * 16 + hi * 4 + i;
                        int col = bw * 128 + nt * 16 + lo;
                        float hold = (it == 0) ? h0v[nt]
                                   : out[(size_t)(b0 + row) * 512 + col];
                        float v = hold * (1.f + tacc[m][nt][i]);  // EPSILON_0 = 1
                        tacc[m][nt][i] = v;                        // stash h_new
                        p[m][i] += v;
                    }
            #pragma unroll
            for (int mask = 1; mask < 16; mask <<= 1)
                #pragma unroll
                for (int m = 0; m < 4; ++m)
                    #pragma unroll
                    for (int i = 0; i < 4; ++i)
                        p[m][i] += __shfl_xor(p[m][i], mask, 64);
            if (lo == 0) {
                #pragma unroll
                for (int m = 0; m < 4; ++m)
                    #pragma unroll
                    for (int i = 0; i < 4; ++i)
                        red[bw][m * 16 + hi * 4 + i] = p[m][i];
            }
            __syncthreads();   // red visible (matches A's post-loop barrier)

            #pragma unroll
            for (int m = 0; m < 4; ++m)
                #pragma unroll
                for (int i = 0; i < 4; ++i) {
                    int row = m * 16 + hi * 4 + i;
                    float S = red[0][row] + red[1][row] + red[2][row] + red[3][row];
                    float inv = 1.f / (S + 1e-20f);
                    #pragma unroll
                    for (int nt = 0; nt < 8; ++nt) {
                        int col = bw * 128 + nt * 16 + lo;
                        float hv = tacc[m][nt][i] * inv;
                        out[(size_t)(b0 + row) * 512 + col] = hv;   // fp32 h store (and final answer)
                        if (it < 4)
                            h_lds[row * 520 + col] = f2bf(hv);      // next iter's A operand
                    }
                }
        }
    }
}

extern "C" void kernel_launch(void* const* d_in, const int* in_sizes, int n_in,
                              void* d_out, int out_size, void* d_ws, size_t ws_size,
                              hipStream_t stream) {
    const float* x   = (const float*)d_in[0];   // [8192][3072]
    const float* wgt = (const float*)d_in[1];   // [512][3072]
    const float* h0  = (const float*)d_in[2];   // [512]
    float* out = (float*)d_out;

    // workspace: X2T 50,331,648 B | W1 3,145,728 B | W2 3,145,728 B | invsum 32,768 B
    unsigned short* X2T = (unsigned short*)d_ws;
    unsigned short* W1  = (unsigned short*)((char*)d_ws + 50331648);
    unsigned short* W2  = (unsigned short*)((char*)d_ws + 53477376);
    float* invsum       = (float*)((char*)d_ws + 56623104);

    prep_sum<<<8192, 64, 0, stream>>>(x, invsum);
    prep_w<<<1536, 256, 0, stream>>>(wgt, W1, W2);
    prep_xt<<<3072, 256, 0, stream>>>(x, invsum, X2T);
    nnmf_main<<<128, 512, 0, stream>>>(X2T, W1, W2, h0, out);
}

// Round 6
// 568.387 us; speedup vs baseline: 2.1981x; 2.1981x over previous
//
#include <hip/hip_runtime.h>

// NNMF fused: B=8192, NIN=3072, NOUT=512, 5 iterations.
// R6: back to the R3 structure (best measured: homogeneous 8 waves, 2 blocks/CU,
// pipelined W-in-regs). Plus:
//  - it0 Phase-A skip: denom(it0) is row-independent => precomputed d0inv vector.
//  - Phase B in fp8 e4m3: W2 quantized x4096, r stored fp8 x16 in LDS,
//    mfma_f32_16x16x32_fp8_fp8, unscale 2^-16 at boundary. Phase A stays bf16.

#define NIN 3072
#define NOUT 512

using bf16x8 = __attribute__((ext_vector_type(8))) short;
using f32x4  = __attribute__((ext_vector_type(4))) float;

__device__ __forceinline__ unsigned short f2bf(float f) {
    unsigned int u = __builtin_bit_cast(unsigned int, f);
    return (unsigned short)((u + 0x7fffu + ((u >> 16) & 1u)) >> 16);  // RNE
}
__device__ __forceinline__ float bf2f(unsigned short s) {
    unsigned int u = ((unsigned int)s) << 16;
    return __builtin_bit_cast(float, u);
}

// ---------------------------------------------------------------------------
// prep_w: W (fp32 [512][3072]) ->
//   W2f8 (fp8 e4m3, x4096, pair-packed for Phase B):
//     byte addr = ((kcg*16 + pr)*64 + l)*16 + h8*8 + j
//     element: n = (pr*2+h8)*16 + (l&15), k = kcg*32 + (l>>4)*8 + j
//   W1 (bf16, Phase A, layout verified R2-R5):
//     W1[((ktg*16+nc)*64 + l)*8 + j] = W[nc*32+(l>>4)*8+j][ktg*16+(l&15)]
// ---------------------------------------------------------------------------
__global__ void prep_w(const float* __restrict__ W,
                       unsigned short* __restrict__ W1,
                       unsigned char* __restrict__ W2) {
    int t = blockIdx.x * 256 + threadIdx.x;   // 0 .. 294911
    if (t < 98304) {
        // W2 fp8 pair-packed
        int f = t >> 6, l = t & 63;
        int kcg = f >> 4, pr = f & 15;
        int kbase = kcg * 32 + ((l >> 4) << 3);
        unsigned int words[4];
        #pragma unroll
        for (int h8 = 0; h8 < 2; ++h8) {
            int n = (pr * 2 + h8) * 16 + (l & 15);
            const float* src = W + (size_t)n * NIN + kbase;
            float v[8];
            #pragma unroll
            for (int j = 0; j < 8; ++j) v[j] = src[j] * 4096.0f;
            int lo32 = __builtin_amdgcn_cvt_pk_fp8_f32(v[0], v[1], 0, false);
            lo32     = __builtin_amdgcn_cvt_pk_fp8_f32(v[2], v[3], lo32, true);
            int hi32 = __builtin_amdgcn_cvt_pk_fp8_f32(v[4], v[5], 0, false);
            hi32     = __builtin_amdgcn_cvt_pk_fp8_f32(v[6], v[7], hi32, true);
            words[h8 * 2]     = (unsigned int)lo32;
            words[h8 * 2 + 1] = (unsigned int)hi32;
        }
        *reinterpret_cast<uint4*>(W2 + (size_t)t * 16) =
            *reinterpret_cast<uint4*>(words);
    } else {
        int u = t - 98304;
        int f = u >> 6, l = u & 63;
        int ktg = f >> 4, nc = f & 15;
        int k = ktg * 16 + (l & 15);
        int nb = nc * 32 + ((l >> 4) << 3);
        unsigned short* dst = W1 + (size_t)u * 8;
        #pragma unroll
        for (int j = 0; j < 8; ++j) dst[j] = f2bf(W[(size_t)(nb + j) * NIN + k]);
    }
}

// ---------------------------------------------------------------------------
// prep_cs: d0inv[k] = 1 / (sum_n h_init[n]*W[n][k] + 1e-20)  (it0 denom, exact fp32)
// ---------------------------------------------------------------------------
__global__ void prep_cs(const float* __restrict__ W, const float* __restrict__ h_init,
                        float* __restrict__ d0inv) {
    int k = blockIdx.x * 256 + threadIdx.x;   // 0..3071
    float s = 0.f;
    for (int n = 0; n < NOUT; ++n) s += h_init[n] * W[(size_t)n * NIN + k];
    d0inv[k] = 1.0f / (s + 1e-20f);
}

// ---------------------------------------------------------------------------
// prep_x: per-row normalize x and store bf16 (coalesced, R3-verified).
// ---------------------------------------------------------------------------
__global__ void prep_x(const float* __restrict__ x, unsigned short* __restrict__ X2) {
    int b = blockIdx.x;
    int t = threadIdx.x;                      // 256 threads
    const float4* r4 = reinterpret_cast<const float4*>(x + (size_t)b * NIN);
    float s = 0.f;
    float4 v0 = r4[t], v1 = r4[t + 256], v2 = r4[t + 512];
    s = v0.x + v0.y + v0.z + v0.w + v1.x + v1.y + v1.z + v1.w + v2.x + v2.y + v2.z + v2.w;
    #pragma unroll
    for (int off = 32; off > 0; off >>= 1) s += __shfl_down(s, off, 64);
    __shared__ float wsum[4];
    int w = t >> 6, l = t & 63;
    if (l == 0) wsum[w] = s;
    __syncthreads();
    float inv = 1.0f / (wsum[0] + wsum[1] + wsum[2] + wsum[3] + 1e-20f);
    unsigned short* orow = X2 + (size_t)b * NIN;
    #pragma unroll
    for (int c = 0; c < 3; ++c) {
        float4 v = (c == 0) ? v0 : (c == 1) ? v1 : v2;
        ushort4 o;
        o.x = f2bf(v.x * inv); o.y = f2bf(v.y * inv);
        o.z = f2bf(v.z * inv); o.w = f2bf(v.w * inv);
        *reinterpret_cast<ushort4*>(orow + (t + c * 256) * 4) = o;
    }
}

// ---------------------------------------------------------------------------
// Main kernel. 256 blocks x 512 threads (8 waves), 32 rows/block, 2 blocks/CU.
// R3 pipelined slot structure; Phase B fp8; it0 skips Phase A (uses d0inv).
// ---------------------------------------------------------------------------
__global__ __launch_bounds__(512, 2) void nnmf_main(
    const unsigned short* __restrict__ X2,
    const unsigned short* __restrict__ W1,
    const unsigned char* __restrict__ W2,
    const float* __restrict__ d0inv,
    const float* __restrict__ h_init,
    float* __restrict__ out)
{
    __shared__ unsigned short h_lds[32 * 520];   // 33.3 KB
    __shared__ unsigned short x_lds[32 * 136];   // 8.7 KB
    __shared__ unsigned char  r8_lds[32 * 144];  // 4.6 KB (fp8 r, stride 144B)
    __shared__ float red[8][32];

    const int tid = threadIdx.x;
    const int w  = tid >> 6;        // wave 0..7
    const int l  = tid & 63;
    const int lo = l & 15;
    const int hi = l >> 4;          // 0..3
    const int b0 = blockIdx.x * 32;

    for (int idx = tid; idx < 32 * 512; idx += 512) {
        int r = idx >> 9, c = idx & 511;
        h_lds[r * 520 + c] = f2bf(h_init[c]);
    }

    // fp32 h in registers, C-layout: row=m*16+hi*4+i, col=w*64+nt*16+lo
    float h_reg[2][4][4];
    #pragma unroll
    for (int nt = 0; nt < 4; ++nt) {
        float hv = h_init[w * 64 + nt * 16 + lo];
        #pragma unroll
        for (int m = 0; m < 2; ++m)
            #pragma unroll
            for (int i = 0; i < 4; ++i)
                h_reg[m][nt][i] = hv;
    }

    // x staging: thread -> (row, 16B chunk)
    const int xrow = tid >> 4, xcc = tid & 15;
    const uint4* xg = reinterpret_cast<const uint4*>(X2 + (size_t)(b0 + xrow) * NIN + xcc * 8);
    unsigned short* xdst = &x_lds[xrow * 136 + xcc * 8];

    // W base pointers
    const unsigned short* w1base = W1 + ((size_t)(w * 16) * 64 + l) * 8;   // +s*65536 el, +nc*512 el
    const unsigned char*  w2base = W2 + (size_t)(w * 2) * 1024 + (size_t)l * 16; // +s*65536 B +kc*16384 B +p*1024 B

    // prime pipeline: x[0] -> LDS, x[1] -> reg, W1[0] -> regs
    *reinterpret_cast<uint4*>(xdst) = xg[0];
    uint4 xnext = xg[16];
    bf16x8 w1buf[16];
    #pragma unroll
    for (int nc = 0; nc < 16; ++nc)
        w1buf[nc] = *reinterpret_cast<const bf16x8*>(w1base + (size_t)nc * 512);
    __syncthreads();

    const float TS = 1.0f / 65536.0f;   // undo W2 x4096 and r x16 scales
    f32x4 tacc[2][4];

    for (int it = 0; it < 5; ++it) {
        #pragma unroll
        for (int m = 0; m < 2; ++m)
            #pragma unroll
            for (int nt = 0; nt < 4; ++nt)
                tacc[m][nt] = (f32x4){0.f, 0.f, 0.f, 0.f};

        for (int s = 0; s < 24; ++s) {
            const int sn  = (s + 1 == 24) ? 0 : s + 1;
            const int sn2 = (s + 2 >= 24) ? (s + 2 - 24) : s + 2;

            // ---- issue W2[s] fp8 loads (8 x dwordx4 = 16 frags; consumed in Phase B)
            uint4 w2v[8];
            {
                const unsigned char* w2p = w2base + (size_t)s * 65536;
                #pragma unroll
                for (int kc = 0; kc < 4; ++kc)
                    #pragma unroll
                    for (int p = 0; p < 2; ++p)
                        w2v[kc * 2 + p] = *reinterpret_cast<const uint4*>(
                            w2p + (size_t)kc * 16384 + p * 1024);
            }

            f32x4 d0 = {0,0,0,0}, d1 = {0,0,0,0};
            float dv = 0.f;
            if (it == 0) {
                dv = d0inv[s * 128 + w * 16 + lo];   // exact it0 denom reciprocal
            } else {
                // ---- Phase A (bf16): denom tiles, W1 operands register-resident
                f32x4 a0a = {0,0,0,0}, a0b = {0,0,0,0}, a1a = {0,0,0,0}, a1b = {0,0,0,0};
                #pragma unroll
                for (int nc = 0; nc < 16; nc += 2) {
                    bf16x8 ha0 = *reinterpret_cast<const bf16x8*>(&h_lds[lo * 520 + nc * 32 + hi * 8]);
                    bf16x8 ha1 = *reinterpret_cast<const bf16x8*>(&h_lds[(16 + lo) * 520 + nc * 32 + hi * 8]);
                    bf16x8 hb0 = *reinterpret_cast<const bf16x8*>(&h_lds[lo * 520 + (nc + 1) * 32 + hi * 8]);
                    bf16x8 hb1 = *reinterpret_cast<const bf16x8*>(&h_lds[(16 + lo) * 520 + (nc + 1) * 32 + hi * 8]);
                    a0a = __builtin_amdgcn_mfma_f32_16x16x32_bf16(ha0, w1buf[nc],     a0a, 0, 0, 0);
                    a1a = __builtin_amdgcn_mfma_f32_16x16x32_bf16(ha1, w1buf[nc],     a1a, 0, 0, 0);
                    a0b = __builtin_amdgcn_mfma_f32_16x16x32_bf16(hb0, w1buf[nc + 1], a0b, 0, 0, 0);
                    a1b = __builtin_amdgcn_mfma_f32_16x16x32_bf16(hb1, w1buf[nc + 1], a1b, 0, 0, 0);
                }
                d0 = a0a + a0b;
                d1 = a1a + a1b;
            }

            // ---- r = 16 * x * rcp(denom + eps) -> fp8 in r8_lds
            #pragma unroll
            for (int i = 0; i < 4; ++i) {
                int row0 = hi * 4 + i;
                float x0 = bf2f(x_lds[row0 * 136 + w * 16 + lo]) * 16.0f;
                float x1 = bf2f(x_lds[(16 + row0) * 136 + w * 16 + lo]) * 16.0f;
                float r0, r1;
                if (it == 0) { r0 = x0 * dv; r1 = x1 * dv; }
                else {
                    r0 = x0 * __builtin_amdgcn_rcpf(d0[i] + 1e-20f);
                    r1 = x1 * __builtin_amdgcn_rcpf(d1[i] + 1e-20f);
                }
                int c0 = __builtin_amdgcn_cvt_pk_fp8_f32(r0, r0, 0, false);
                int c1 = __builtin_amdgcn_cvt_pk_fp8_f32(r1, r1, 0, false);
                r8_lds[row0 * 144 + w * 16 + lo] = (unsigned char)(c0 & 0xff);
                r8_lds[(16 + row0) * 144 + w * 16 + lo] = (unsigned char)(c1 & 0xff);
            }
            __syncthreads();   // barrier A

            // ---- Phase B 1st half (kc 0,1), fp8 MFMA
            #pragma unroll
            for (int kc = 0; kc < 2; ++kc) {
                long long ra0 = *reinterpret_cast<const long long*>(&r8_lds[lo * 144 + kc * 32 + hi * 8]);
                long long ra1 = *reinterpret_cast<const long long*>(&r8_lds[(16 + lo) * 144 + kc * 32 + hi * 8]);
                #pragma unroll
                for (int p = 0; p < 2; ++p) {
                    union { uint4 v; long long q[2]; } u;
                    u.v = w2v[kc * 2 + p];
                    #pragma unroll
                    for (int h8 = 0; h8 < 2; ++h8) {
                        int nt = p * 2 + h8;
                        tacc[0][nt] = __builtin_amdgcn_mfma_f32_16x16x32_fp8_fp8(ra0, u.q[h8], tacc[0][nt], 0, 0, 0);
                        tacc[1][nt] = __builtin_amdgcn_mfma_f32_16x16x32_fp8_fp8(ra1, u.q[h8], tacc[1][nt], 0, 0, 0);
                    }
                }
            }

            // ---- reload w1buf with W1[sn] (skip during it0 except last slot)
            if (it > 0 || s == 23) {
                const unsigned short* w1p = w1base + (size_t)sn * 65536;
                #pragma unroll
                for (int nc = 0; nc < 16; ++nc)
                    w1buf[nc] = *reinterpret_cast<const bf16x8*>(w1p + (size_t)nc * 512);
            }

            // ---- Phase B 2nd half (kc 2,3)
            #pragma unroll
            for (int kc = 2; kc < 4; ++kc) {
                long long ra0 = *reinterpret_cast<const long long*>(&r8_lds[lo * 144 + kc * 32 + hi * 8]);
                long long ra1 = *reinterpret_cast<const long long*>(&r8_lds[(16 + lo) * 144 + kc * 32 + hi * 8]);
                #pragma unroll
                for (int p = 0; p < 2; ++p) {
                    union { uint4 v; long long q[2]; } u;
                    u.v = w2v[kc * 2 + p];
                    #pragma unroll
                    for (int h8 = 0; h8 < 2; ++h8) {
                        int nt = p * 2 + h8;
                        tacc[0][nt] = __builtin_amdgcn_mfma_f32_16x16x32_fp8_fp8(ra0, u.q[h8], tacc[0][nt], 0, 0, 0);
                        tacc[1][nt] = __builtin_amdgcn_mfma_f32_16x16x32_fp8_fp8(ra1, u.q[h8], tacc[1][nt], 0, 0, 0);
                    }
                }
            }

            // ---- stage x[s+1]
            *reinterpret_cast<uint4*>(xdst) = xnext;
            xnext = xg[sn2 * 16];
            __syncthreads();   // barrier B
        }

        // ---- boundary: h_new = normalize(h * (1 + t*2^-16)), fp32 in regs
        float p[2][4];
        #pragma unroll
        for (int m = 0; m < 2; ++m)
            #pragma unroll
            for (int i = 0; i < 4; ++i) p[m][i] = 0.f;

        #pragma unroll
        for (int m = 0; m < 2; ++m)
            #pragma unroll
            for (int nt = 0; nt < 4; ++nt)
                #pragma unroll
                for (int i = 0; i < 4; ++i) {
                    float v = h_reg[m][nt][i] * (1.f + tacc[m][nt][i] * TS);  // EPSILON_0 = 1
                    h_reg[m][nt][i] = v;
                    p[m][i] += v;
                }
        #pragma unroll
        for (int mask = 1; mask < 16; mask <<= 1)
            #pragma unroll
            for (int m = 0; m < 2; ++m)
                #pragma unroll
                for (int i = 0; i < 4; ++i)
                    p[m][i] += __shfl_xor(p[m][i], mask, 64);
        if (lo == 0) {
            #pragma unroll
            for (int m = 0; m < 2; ++m)
                #pragma unroll
                for (int i = 0; i < 4; ++i)
                    red[w][m * 16 + hi * 4 + i] = p[m][i];
        }
        __syncthreads();
        float inv[2][4];
        #pragma unroll
        for (int m = 0; m < 2; ++m)
            #pragma unroll
            for (int i = 0; i < 4; ++i) {
                int row = m * 16 + hi * 4 + i;
                float S = 0.f;
                #pragma unroll
                for (int ww = 0; ww < 8; ++ww) S += red[ww][row];
                inv[m][i] = 1.f / (S + 1e-20f);
            }

        if (it < 4) {
            #pragma unroll
            for (int m = 0; m < 2; ++m)
                #pragma unroll
                for (int nt = 0; nt < 4; ++nt)
                    #pragma unroll
                    for (int i = 0; i < 4; ++i) {
                        int row = m * 16 + hi * 4 + i;
                        int col = w * 64 + nt * 16 + lo;
                        float hv = h_reg[m][nt][i] * inv[m][i];
                        h_reg[m][nt][i] = hv;
                        h_lds[row * 520 + col] = f2bf(hv);
                    }
            __syncthreads();
        } else {
            #pragma unroll
            for (int m = 0; m < 2; ++m)
                #pragma unroll
                for (int nt = 0; nt < 4; ++nt)
                    #pragma unroll
                    for (int i = 0; i < 4; ++i) {
                        int row = m * 16 + hi * 4 + i;
                        int col = w * 64 + nt * 16 + lo;
                        out[(size_t)(b0 + row) * 512 + col] = h_reg[m][nt][i] * inv[m][i];
                    }
        }
    }
}

extern "C" void kernel_launch(void* const* d_in, const int* in_sizes, int n_in,
                              void* d_out, int out_size, void* d_ws, size_t ws_size,
                              hipStream_t stream) {
    const float* x   = (const float*)d_in[0];   // [8192][3072]
    const float* wgt = (const float*)d_in[1];   // [512][3072]
    const float* h0  = (const float*)d_in[2];   // [512]
    float* out = (float*)d_out;

    // ws: X2 bf16 50,331,648 | W1 bf16 3,145,728 | W2 fp8 1,572,864 | d0inv 12,288
    unsigned short* X2 = (unsigned short*)d_ws;
    unsigned short* W1 = (unsigned short*)((char*)d_ws + 50331648);
    unsigned char*  W2 = (unsigned char*)((char*)d_ws + 53477376);
    float* d0inv       = (float*)((char*)d_ws + 55050240);

    prep_w<<<1152, 256, 0, stream>>>(wgt, W1, W2);
    prep_cs<<<12, 256, 0, stream>>>(wgt, h0, d0inv);
    prep_x<<<8192, 256, 0, stream>>>(x, X2);
    nnmf_main<<<256, 512, 0, stream>>>(X2, W1, W2, d0inv, h0, out);
}